// Round 9
// baseline (260.794 us; speedup 1.0000x reference)
//
#include <hip/hip_runtime.h>
#include <math.h>

#define G    4      // segments per block
#define CAP  104    // max staged rows per group (mean 80, sd~9 -> ~0.4% fallback)

// ---------------------------------------------------------------------------
__global__ void k_segstarts(const int* __restrict__ map, int* __restrict__ starts,
                            int V, int S) {
    int i = blockIdx.x * blockDim.x + threadIdx.x;
    if (i >= V) return;
    int cur  = map[i];
    int prev = (i == 0) ? -1 : map[i - 1];
    for (int s = prev + 1; s <= cur; ++s) starts[s] = i;
    if (i == V - 1) {
        for (int s = cur + 1; s <= S; ++s) starts[s] = V;
    }
}

// M[i][j] = sum_h Wk[h][i]*Wv[h][j] ;  Wt[i][o] = Wo[o][i]
__global__ void k_prep(const float* __restrict__ Wk, const float* __restrict__ Wv,
                       const float* __restrict__ Wo,
                       float* __restrict__ M, float* __restrict__ Wt) {
    int i = blockIdx.x;
    int j = threadIdx.x;
    float acc = 0.f;
#pragma unroll 8
    for (int h = 0; h < 128; ++h)
        acc += Wk[h * 128 + i] * Wv[h * 128 + j];
    M[i * 128 + j]  = acc;
    Wt[i * 128 + j] = Wo[j * 128 + i];
}

__device__ __forceinline__ float bfu_lo(unsigned u) {            // low bf16
    return __uint_as_float(u << 16);
}
__device__ __forceinline__ float bfu_hi(unsigned u) {            // high bf16
    return __uint_as_float(u & 0xFFFF0000u);
}

// ---------------------------------------------------------------------------
// k_main: one block = G consecutive segments = one contiguous row range of E,
// staged ONCE into LDS as bf16 (27 KB) -> 5 blocks/CU (20 waves).
// Phases: stage -> mean -> qGEMM -> attn -> outGEMM (4 barriers).
// ---------------------------------------------------------------------------
__global__ __launch_bounds__(256, 5) void k_main(
    const float* __restrict__ E, const int* __restrict__ starts,
    const float* __restrict__ M, const float* __restrict__ Wt,
    float* __restrict__ out, int V, int S)
{
    __shared__ unsigned sA[CAP][64];   // bf16-packed rows (26.6 KB)
    __shared__ float    sE[G][128];    // ebar, later etilde (2 KB)
    __shared__ float    sQ[G][128];    // q (2 KB)

    const int tid  = threadIdx.x;
    const int w    = tid >> 6;       // wave id = local segment id
    const int lane = tid & 63;
    const int s0   = blockIdx.x * G;

    const int se    = min(s0 + G, S);
    const int gr0   = starts[s0];
    const int nrows = starts[se] - gr0;
    const bool staged = (nrows <= CAP);

    const int c  = lane & 31;        // column quad (cols c*4 .. c*4+3)
    const int g  = lane >> 5;        // row parity / i-half selector
    const int jq = c;                // GEMM j-quad
    const int ih = g;                // GEMM i-half

    // ---------------- stage: E rows -> bf16 LDS ---------------------------
    if (staged && nrows > 0) {
        const int q4 = tid & 31;
        const int rr = tid >> 5;                 // 0..7, stride 8
        const float* gp = E + (size_t)gr0 * 128 + q4 * 4;
        float4 t[7];
#pragma unroll
        for (int k = 0; k < 7; ++k) {
            const int r = min(rr + k * 8, nrows - 1);
            t[k] = *(const float4*)(gp + (size_t)r * 128);
        }
#pragma unroll
        for (int k = 0; k < 7; ++k) {
            uint2 u;
            u.x = (__float_as_uint(t[k].x) >> 16) | (__float_as_uint(t[k].y) & 0xFFFF0000u);
            u.y = (__float_as_uint(t[k].z) >> 16) | (__float_as_uint(t[k].w) & 0xFFFF0000u);
            *(uint2*)&sA[rr + k * 8][q4 * 2] = u;     // rows>=nrows: dup, unread
        }
        float4 t2[6];
#pragma unroll
        for (int k = 0; k < 6; ++k) {
            const int r = min(rr + (k + 7) * 8, nrows - 1);
            t2[k] = *(const float4*)(gp + (size_t)r * 128);
        }
#pragma unroll
        for (int k = 0; k < 6; ++k) {
            uint2 u;
            u.x = (__float_as_uint(t2[k].x) >> 16) | (__float_as_uint(t2[k].y) & 0xFFFF0000u);
            u.y = (__float_as_uint(t2[k].z) >> 16) | (__float_as_uint(t2[k].w) & 0xFFFF0000u);
            *(uint2*)&sA[rr + (k + 7) * 8][q4 * 2] = u;
        }
    }
    __syncthreads();

    // per-wave segment meta
    const int segi = s0 + w;
    int r0 = 0, n = 0, off = 0;
    if (segi < S) {
        r0  = starts[segi];
        n   = starts[segi + 1] - r0;
        off = r0 - gr0;
    }

    // ---------------- mean: ebar[w] ----------------------------------------
    {
        float4 sum = make_float4(0.f, 0.f, 0.f, 0.f);
        if (segi < S && n > 0) {
            if (staged) {
#pragma unroll 4
                for (int rp = 0; rp < n; rp += 2) {
                    const int row = rp + g;
                    const int rcl = min(row, n - 1);
                    const uint2 u = *(const uint2*)&sA[off + rcl][c * 2];
                    const float m = (row < n) ? 1.f : 0.f;
                    sum.x += m * bfu_lo(u.x); sum.y += m * bfu_hi(u.x);
                    sum.z += m * bfu_lo(u.y); sum.w += m * bfu_hi(u.y);
                }
            } else {
                const float* bp = E + (size_t)r0 * 128 + c * 4;
#pragma unroll 4
                for (int rp = 0; rp < n; rp += 2) {
                    const int row = rp + g;
                    const int rcl = min(row, n - 1);
                    const float4 ev = *(const float4*)(bp + (size_t)rcl * 128);
                    const float m = (row < n) ? 1.f : 0.f;
                    sum.x += m * ev.x; sum.y += m * ev.y;
                    sum.z += m * ev.z; sum.w += m * ev.w;
                }
            }
            sum.x += __shfl_xor(sum.x, 32);
            sum.y += __shfl_xor(sum.y, 32);
            sum.z += __shfl_xor(sum.z, 32);
            sum.w += __shfl_xor(sum.w, 32);
            const float inv = 1.0f / (float)n;
            sum.x *= inv; sum.y *= inv; sum.z *= inv; sum.w *= inv;
        }
        if (g == 0)
            *(float4*)&sE[w][c * 4] = sum;    // zeros when segi>=S or n==0
    }
    __syncthreads();

    // ---------------- q GEMM: sQ[w] = sE[w] @ M ----------------------------
    {
        const float* Mb = M + (size_t)(ih * 64) * 128 + jq * 4;
        float4 a = make_float4(0.f, 0.f, 0.f, 0.f);
#pragma unroll 8
        for (int i = 0; i < 64; ++i) {
            const float4 m4 = *(const float4*)(Mb + (size_t)i * 128);
            const float e = sE[w][ih * 64 + i];
            a.x += e * m4.x; a.y += e * m4.y;
            a.z += e * m4.z; a.w += e * m4.w;
        }
        a.x += __shfl_xor(a.x, 32);
        a.y += __shfl_xor(a.y, 32);
        a.z += __shfl_xor(a.z, 32);
        a.w += __shfl_xor(a.w, 32);
        if (ih == 0)
            *(float4*)&sQ[w][jq * 4] = a;
    }
    __syncthreads();

    // ---------------- attn: merged scores + exp + weighted sum -------------
    {
        float4 acc = make_float4(0.f, 0.f, 0.f, 0.f);
        float Z = 0.f;
        if (segi < S && n > 0) {
            const float4 qv = *(const float4*)&sQ[w][c * 4];
            if (staged) {
#pragma unroll 4
                for (int rp = 0; rp < n; rp += 2) {
                    const int row = rp + g;
                    const int rcl = min(row, n - 1);
                    const uint2 u = *(const uint2*)&sA[off + rcl][c * 2];
                    const float e0 = bfu_lo(u.x), e1 = bfu_hi(u.x);
                    const float e2 = bfu_lo(u.y), e3 = bfu_hi(u.y);
                    float pd = e0 * qv.x + e1 * qv.y + e2 * qv.z + e3 * qv.w;
                    pd += __shfl_xor(pd, 1);
                    pd += __shfl_xor(pd, 2);
                    pd += __shfl_xor(pd, 4);
                    pd += __shfl_xor(pd, 8);
                    pd += __shfl_xor(pd, 16);
                    const float wgt = (row < n) ? __expf(pd) : 0.f;
                    Z += wgt;
                    acc.x += wgt * e0; acc.y += wgt * e1;
                    acc.z += wgt * e2; acc.w += wgt * e3;
                }
            } else {
                const float* bp = E + (size_t)r0 * 128 + c * 4;
#pragma unroll 4
                for (int rp = 0; rp < n; rp += 2) {
                    const int row = rp + g;
                    const int rcl = min(row, n - 1);
                    const float4 ev = *(const float4*)(bp + (size_t)rcl * 128);
                    float pd = ev.x * qv.x + ev.y * qv.y
                             + ev.z * qv.z + ev.w * qv.w;
                    pd += __shfl_xor(pd, 1);
                    pd += __shfl_xor(pd, 2);
                    pd += __shfl_xor(pd, 4);
                    pd += __shfl_xor(pd, 8);
                    pd += __shfl_xor(pd, 16);
                    const float wgt = (row < n) ? __expf(pd) : 0.f;
                    Z += wgt;
                    acc.x += wgt * ev.x; acc.y += wgt * ev.y;
                    acc.z += wgt * ev.z; acc.w += wgt * ev.w;
                }
            }
            acc.x += __shfl_xor(acc.x, 32);
            acc.y += __shfl_xor(acc.y, 32);
            acc.z += __shfl_xor(acc.z, 32);
            acc.w += __shfl_xor(acc.w, 32);
            Z     += __shfl_xor(Z, 32);
            const float invZ = 1.0f / Z;
            acc.x *= invZ; acc.y *= invZ; acc.z *= invZ; acc.w *= invZ;
        }
        if (g == 0)
            *(float4*)&sE[w][c * 4] = acc;    // etilde (zeros if empty)
    }
    __syncthreads();

    // ---------------- out GEMM: out[segi] = sE[w] @ Wt ---------------------
    {
        const float* Wb = Wt + (size_t)(ih * 64) * 128 + jq * 4;
        float4 a = make_float4(0.f, 0.f, 0.f, 0.f);
#pragma unroll 8
        for (int i = 0; i < 64; ++i) {
            const float4 m4 = *(const float4*)(Wb + (size_t)i * 128);
            const float e = sE[w][ih * 64 + i];
            a.x += e * m4.x; a.y += e * m4.y;
            a.z += e * m4.z; a.w += e * m4.w;
        }
        a.x += __shfl_xor(a.x, 32);
        a.y += __shfl_xor(a.y, 32);
        a.z += __shfl_xor(a.z, 32);
        a.w += __shfl_xor(a.w, 32);
        if (ih == 0 && segi < S)
            *(float4*)&out[(size_t)segi * 128 + jq * 4] = a;
    }
}

// ---------------------------------------------------------------------------
extern "C" void kernel_launch(void* const* d_in, const int* in_sizes, int n_in,
                              void* d_out, int out_size, void* d_ws, size_t ws_size,
                              hipStream_t stream) {
    const float* E   = (const float*)d_in[0];
    const int*   map = (const int*)d_in[1];
    const float* Wk  = (const float*)d_in[3];
    const float* Wv  = (const float*)d_in[4];
    const float* Wo  = (const float*)d_in[5];
    float* out = (float*)d_out;

    const int V = in_sizes[1];
    const int S = out_size / 128;

    char* p = (char*)d_ws;
    auto alloc = [&](size_t b) {
        char* r = p;
        p += (b + 255) & ~(size_t)255;
        return r;
    };
    int*   starts = (int*)alloc((size_t)(S + 1) * sizeof(int));
    float* M      = (float*)alloc(128 * 128 * sizeof(float));
    float* Wt     = (float*)alloc(128 * 128 * sizeof(float));

    k_segstarts<<<(V + 255) / 256, 256, 0, stream>>>(map, starts, V, S);
    k_prep<<<128, 128, 0, stream>>>(Wk, Wv, Wo, M, Wt);
    k_main<<<(S + G - 1) / G, 256, 0, stream>>>(E, starts, M, Wt, out, V, S);
}